// Round 1
// baseline (243.679 us; speedup 1.0000x reference)
//
#include <hip/hip_runtime.h>
#include <hip/hip_bf16.h>

#define NN 40000
#define NE 640000
#define DD 128

typedef unsigned short u16;
typedef unsigned int u32;

__device__ __forceinline__ float b2f(u32 bits16) {
  return __uint_as_float(bits16 << 16);
}
__device__ __forceinline__ u16 f2b(float f) {
  __hip_bfloat16 h = __float2bfloat16(f);
  return *reinterpret_cast<u16*>(&h);
}

// ---------------- utility ----------------
__global__ void zero_kernel(int* __restrict__ p, int n) {
  int i = blockIdx.x * 256 + threadIdx.x;
  if (i < n) p[i] = 0;
}

__global__ void hist_kernel(const int* __restrict__ dst, int* __restrict__ deg) {
  int e = blockIdx.x * 256 + threadIdx.x;
  if (e < NE) atomicAdd(&deg[dst[e]], 1);
}

// inclusive scan within 256-elem blocks; rowptr[i+1] = partial, bsum[b] = block total
__global__ void scan1_kernel(const int* __restrict__ deg, int* __restrict__ rowptr,
                             int* __restrict__ bsum) {
  __shared__ int s[256];
  int tid = threadIdx.x;
  int i = blockIdx.x * 256 + tid;
  int v = (i < NN) ? deg[i] : 0;
  s[tid] = v;
  __syncthreads();
  for (int off = 1; off < 256; off <<= 1) {
    int t = (tid >= off) ? s[tid - off] : 0;
    __syncthreads();
    s[tid] += t;
    __syncthreads();
  }
  if (i < NN) rowptr[i + 1] = s[tid];
  if (tid == 255) bsum[blockIdx.x] = s[255];
}

// exclusive scan of bsum[nb] in one block
__global__ void scan2_kernel(int* __restrict__ bsum, int nb) {
  __shared__ int s[256];
  int tid = threadIdx.x;
  int v = (tid < nb) ? bsum[tid] : 0;
  s[tid] = v;
  __syncthreads();
  for (int off = 1; off < 256; off <<= 1) {
    int t = (tid >= off) ? s[tid - off] : 0;
    __syncthreads();
    s[tid] += t;
    __syncthreads();
  }
  if (tid < nb) bsum[tid] = s[tid] - v;  // exclusive
}

__global__ void scan3_kernel(int* __restrict__ rowptr, const int* __restrict__ bsum,
                             const int* __restrict__ deg, float* __restrict__ invdeg) {
  int i = blockIdx.x * 256 + threadIdx.x;
  if (i < NN) {
    rowptr[i + 1] += bsum[i >> 8];
    int d = deg[i];
    invdeg[i] = 1.0f / (float)(d > 1 ? d : 1);
  }
  if (i == 0) rowptr[0] = 0;
}

__global__ void cursor_kernel(const int* __restrict__ rowptr, int* __restrict__ cursor) {
  int i = blockIdx.x * 256 + threadIdx.x;
  if (i < NN) cursor[i] = rowptr[i];
}

__global__ void fill_kernel(const int* __restrict__ src, const int* __restrict__ dst,
                            int* __restrict__ cursor, int* __restrict__ csr) {
  int e = blockIdx.x * 256 + threadIdx.x;
  if (e < NE) {
    int d = dst[e];
    int p = atomicAdd(&cursor[d], 1);
    csr[p] = src[e];
  }
}

__global__ void tob_kernel(const float* __restrict__ x, u16* __restrict__ xb) {
  int i = blockIdx.x * 256 + threadIdx.x;  // 4 elems per thread, exact fit
  float4 v = *(const float4*)(x + (size_t)i * 4);
  ushort4 o;
  o.x = f2b(v.x); o.y = f2b(v.y); o.z = f2b(v.z); o.w = f2b(v.w);
  *(ushort4*)(xb + (size_t)i * 4) = o;
}

// ---------------- aggregation: 16 lanes per node, 8 bf16 per lane ----------------
__global__ __launch_bounds__(256) void agg_kernel(
    const u16* __restrict__ xb, const int* __restrict__ rowptr,
    const int* __restrict__ csr, const float* __restrict__ invdeg,
    u16* __restrict__ outb) {
  const int t = threadIdx.x;
  const int li = t & 15;
  const int node = blockIdx.x * 16 + (t >> 4);
  const int s0 = rowptr[node];
  const int s1 = rowptr[node + 1];
  float acc[8] = {0.f, 0.f, 0.f, 0.f, 0.f, 0.f, 0.f, 0.f};
  for (int e = s0; e < s1; ++e) {
    const int srcn = csr[e];
    const uint4 v = *(const uint4*)(xb + (size_t)srcn * DD + li * 8);
    acc[0] += __uint_as_float(v.x << 16);
    acc[1] += __uint_as_float(v.x & 0xffff0000u);
    acc[2] += __uint_as_float(v.y << 16);
    acc[3] += __uint_as_float(v.y & 0xffff0000u);
    acc[4] += __uint_as_float(v.z << 16);
    acc[5] += __uint_as_float(v.z & 0xffff0000u);
    acc[6] += __uint_as_float(v.w << 16);
    acc[7] += __uint_as_float(v.w & 0xffff0000u);
  }
  const float sc = invdeg[node];
  u16 r[8];
#pragma unroll
  for (int j = 0; j < 8; ++j) r[j] = f2b(acc[j] * sc);
  uint4 o;
  o.x = (u32)r[0] | ((u32)r[1] << 16);
  o.y = (u32)r[2] | ((u32)r[3] << 16);
  o.z = (u32)r[4] | ((u32)r[5] << 16);
  o.w = (u32)r[6] | ((u32)r[7] << 16);
  *(uint4*)(outb + (size_t)node * DD + li * 8) = o;
}

// ---------------- fused GEMM: out = A1@Wl + A2@Wr + b (+relu) ----------------
// A1, A2: [NN][128] bf16. Wl, Wr: [128][128] f32. 64 rows x 128 cols per block.
template <int OUT_BF16, int RELU>
__global__ __launch_bounds__(256) void gemm_kernel(
    const u16* __restrict__ A1, const u16* __restrict__ A2,
    const float* __restrict__ Wl, const float* __restrict__ Wr,
    const float* __restrict__ bias, void* __restrict__ outp) {
  __shared__ float Wlds[64][128];
  __shared__ float Alds[64][72];  // [row][k], stride 72 keeps b128 writes aligned
  const int t = threadIdx.x;
  const int tx = t & 31;   // col group: c0 = tx*4
  const int ty = t >> 5;   // row group: r0 = ty*8
  const int m0 = blockIdx.x * 64;

  float acc[8][4];
#pragma unroll
  for (int i = 0; i < 8; ++i)
#pragma unroll
    for (int j = 0; j < 4; ++j) acc[i][j] = 0.f;

  for (int chunk = 0; chunk < 4; ++chunk) {
    const u16* A = (chunk < 2) ? A1 : A2;
    const float* W = (chunk < 2) ? Wl : Wr;
    const int kb = (chunk & 1) * 64;

    // stage W[kb..kb+63][0..127] -> Wlds
    {
      const int f = t & 31, r0s = t >> 5;
#pragma unroll
      for (int rr = r0s; rr < 64; rr += 8) {
        *(float4*)&Wlds[rr][f * 4] = *(const float4*)&W[(size_t)(kb + rr) * 128 + f * 4];
      }
    }
    // stage A rows m0..m0+63, k kb..kb+63 (bf16 -> f32) -> Alds[row][k]
    {
      const int lk = t & 15, r0s = t >> 4;
#pragma unroll
      for (int rr = r0s; rr < 64; rr += 16) {
        const u16* ap = A + (size_t)(m0 + rr) * DD + kb + lk * 4;
        ushort4 a4 = *(const ushort4*)ap;
        float4 af;
        af.x = b2f(a4.x); af.y = b2f(a4.y); af.z = b2f(a4.z); af.w = b2f(a4.w);
        *(float4*)&Alds[rr][lk * 4] = af;
      }
    }
    __syncthreads();

#pragma unroll 8
    for (int k = 0; k < 64; ++k) {
      const float4 w = *(const float4*)&Wlds[k][tx * 4];
#pragma unroll
      for (int i = 0; i < 8; ++i) {
        const float a = Alds[ty * 8 + i][k];
        acc[i][0] = fmaf(a, w.x, acc[i][0]);
        acc[i][1] = fmaf(a, w.y, acc[i][1]);
        acc[i][2] = fmaf(a, w.z, acc[i][2]);
        acc[i][3] = fmaf(a, w.w, acc[i][3]);
      }
    }
    __syncthreads();
  }

  const int c0 = tx * 4;
  const float4 bb = *(const float4*)&bias[c0];
#pragma unroll
  for (int i = 0; i < 8; ++i) {
    const int row = m0 + ty * 8 + i;
    float o0 = acc[i][0] + bb.x;
    float o1 = acc[i][1] + bb.y;
    float o2 = acc[i][2] + bb.z;
    float o3 = acc[i][3] + bb.w;
    if (RELU) {
      o0 = fmaxf(o0, 0.f); o1 = fmaxf(o1, 0.f);
      o2 = fmaxf(o2, 0.f); o3 = fmaxf(o3, 0.f);
    }
    if (OUT_BF16) {
      ushort4 s4;
      s4.x = f2b(o0); s4.y = f2b(o1); s4.z = f2b(o2); s4.w = f2b(o3);
      *(ushort4*)((u16*)outp + (size_t)row * DD + c0) = s4;
    } else {
      float4 f4 = make_float4(o0, o1, o2, o3);
      *(float4*)((float*)outp + (size_t)row * DD + c0) = f4;
    }
  }
}

// ---------------- launch ----------------
extern "C" void kernel_launch(void* const* d_in, const int* in_sizes, int n_in,
                              void* d_out, int out_size, void* d_ws, size_t ws_size,
                              hipStream_t stream) {
  const float* x = (const float*)d_in[0];
  const int* ei = (const int*)d_in[1];
  const int* srcv = ei;          // edge_index[0]
  const int* dstv = ei + NE;     // edge_index[1]
  const float* W1l = (const float*)d_in[2];
  const float* b1 = (const float*)d_in[3];
  const float* W1r = (const float*)d_in[4];
  const float* W2l = (const float*)d_in[5];
  const float* b2 = (const float*)d_in[6];
  const float* W2r = (const float*)d_in[7];
  float* out = (float*)d_out;

  char* ws = (char*)d_ws;
  int* deg = (int*)(ws + 0);               // 160000 B
  int* rowptr = (int*)(ws + 160256);       // 160004 B
  int* cursor = (int*)(ws + 320512);       // 160000 B
  int* bsum = (int*)(ws + 480512);         // 4096 B
  float* invdeg = (float*)(ws + 484608);   // 160000 B
  int* csr = (int*)(ws + 644608);          // 2560000 B
  u16* xb = (u16*)(ws + 3205376);          // 10240000 B
  u16* aggb = (u16*)(ws + 13445376);       // 10240000 B
  u16* hb = (u16*)(ws + 23685376);         // 10240000 B  (end ~33.9 MB)

  const int nbN = (NN + 255) / 256;   // 157
  const int nbE = NE / 256;           // 2500

  zero_kernel<<<nbN, 256, 0, stream>>>(deg, NN);
  hist_kernel<<<nbE, 256, 0, stream>>>(dstv, deg);
  scan1_kernel<<<nbN, 256, 0, stream>>>(deg, rowptr, bsum);
  scan2_kernel<<<1, 256, 0, stream>>>(bsum, nbN);
  scan3_kernel<<<nbN, 256, 0, stream>>>(rowptr, bsum, deg, invdeg);
  cursor_kernel<<<nbN, 256, 0, stream>>>(rowptr, cursor);
  fill_kernel<<<nbE, 256, 0, stream>>>(srcv, dstv, cursor, csr);
  tob_kernel<<<(NN * DD / 4 + 255) / 256, 256, 0, stream>>>(x, xb);

  // layer 1
  agg_kernel<<<NN / 16, 256, 0, stream>>>(xb, rowptr, csr, invdeg, aggb);
  gemm_kernel<1, 1><<<NN / 64, 256, 0, stream>>>(aggb, xb, W1l, W1r, b1, (void*)hb);
  // layer 2
  agg_kernel<<<NN / 16, 256, 0, stream>>>(hb, rowptr, csr, invdeg, aggb);
  gemm_kernel<0, 0><<<NN / 64, 256, 0, stream>>>(aggb, hb, W2l, W2r, b2, (void*)out);
}

// Round 2
// 195.271 us; speedup vs baseline: 1.2479x; 1.2479x over previous
//
#include <hip/hip_runtime.h>
#include <hip/hip_bf16.h>

#define NN 40000
#define NE 640000
#define DD 128

typedef unsigned short u16;
typedef unsigned int u32;
typedef __attribute__((ext_vector_type(8))) short short8v;
typedef __attribute__((ext_vector_type(4))) float f32x4;

__device__ __forceinline__ float b2f(u32 bits16) {
  return __uint_as_float(bits16 << 16);
}
__device__ __forceinline__ u16 f2b(float f) {
  __hip_bfloat16 h = __float2bfloat16(f);
  return *reinterpret_cast<u16*>(&h);
}

// ---------------- CSR build ----------------
__global__ void hist_kernel(const int* __restrict__ dst, int* __restrict__ deg) {
  int e = blockIdx.x * 256 + threadIdx.x;
  if (e < NE) atomicAdd(&deg[dst[e]], 1);
}

__global__ void scan1_kernel(const int* __restrict__ deg, int* __restrict__ rowptr,
                             int* __restrict__ bsum) {
  __shared__ int s[256];
  int tid = threadIdx.x;
  int i = blockIdx.x * 256 + tid;
  int v = (i < NN) ? deg[i] : 0;
  s[tid] = v;
  __syncthreads();
  for (int off = 1; off < 256; off <<= 1) {
    int t = (tid >= off) ? s[tid - off] : 0;
    __syncthreads();
    s[tid] += t;
    __syncthreads();
  }
  if (i < NN) rowptr[i + 1] = s[tid];
  if (tid == 255) bsum[blockIdx.x] = s[255];
}

__global__ void scan2_kernel(int* __restrict__ bsum, int nb) {
  __shared__ int s[256];
  int tid = threadIdx.x;
  int v = (tid < nb) ? bsum[tid] : 0;
  s[tid] = v;
  __syncthreads();
  for (int off = 1; off < 256; off <<= 1) {
    int t = (tid >= off) ? s[tid - off] : 0;
    __syncthreads();
    s[tid] += t;
    __syncthreads();
  }
  if (tid < nb) bsum[tid] = s[tid] - v;  // exclusive
}

// finalize rowptr, write invdeg, and initialize cursor (fused old cursor_kernel)
__global__ void scan3_kernel(int* __restrict__ rowptr, const int* __restrict__ bsum,
                             const int* __restrict__ deg, float* __restrict__ invdeg,
                             int* __restrict__ cursor) {
  int i = blockIdx.x * 256 + threadIdx.x;
  if (i < NN) {
    int v = rowptr[i + 1] + bsum[i >> 8];
    rowptr[i + 1] = v;
    if (i + 1 < NN) cursor[i + 1] = v;
    int d = deg[i];
    invdeg[i] = 1.0f / (float)(d > 1 ? d : 1);
  }
  if (i == 0) {
    rowptr[0] = 0;
    cursor[0] = 0;
  }
}

__global__ void fill_kernel(const int* __restrict__ src, const int* __restrict__ dst,
                            int* __restrict__ cursor, int* __restrict__ csr) {
  int e = blockIdx.x * 256 + threadIdx.x;
  if (e < NE) {
    int d = dst[e];
    int p = atomicAdd(&cursor[d], 1);
    csr[p] = src[e];
  }
}

// ---------------- dtype prep ----------------
__global__ void tob_kernel(const float* __restrict__ x, u16* __restrict__ xb) {
  int i = blockIdx.x * 256 + threadIdx.x;  // 4 elems/thread, exact fit
  float4 v = *(const float4*)(x + (size_t)i * 4);
  ushort4 o;
  o.x = f2b(v.x); o.y = f2b(v.y); o.z = f2b(v.z); o.w = f2b(v.w);
  *(ushort4*)(xb + (size_t)i * 4) = o;
}

// Wt[n][k] bf16, k in [0,256): k<128 -> Wl[k][n], else Wr[k-128][n]
__global__ void wcvt_kernel(const float* __restrict__ Wl, const float* __restrict__ Wr,
                            u16* __restrict__ Wt) {
  int i = blockIdx.x * 256 + threadIdx.x;  // 128*256 = 32768 -> 128 blocks
  int n = i >> 8, k = i & 255;
  const float* W = (k < 128) ? Wl : Wr;
  int kk = k & 127;
  Wt[i] = f2b(W[(size_t)kk * 128 + n]);
}

// ---------------- aggregation: 1 wave per node, 4 edge-slots x 16 lanes ----------------
__global__ __launch_bounds__(256) void agg_kernel(
    const u16* __restrict__ xb, const int* __restrict__ rowptr,
    const int* __restrict__ csr, const float* __restrict__ invdeg,
    u16* __restrict__ outb) {
  const int t = threadIdx.x;
  const int lane = t & 63;
  const int li = lane & 15;   // feature group: 8 bf16 at li*8
  const int eo = lane >> 4;   // edge slot 0..3
  const int node = blockIdx.x * 4 + (t >> 6);
  const int s0 = rowptr[node];
  const int s1 = rowptr[node + 1];
  float acc[8] = {0.f, 0.f, 0.f, 0.f, 0.f, 0.f, 0.f, 0.f};
  for (int e = s0 + eo; e < s1; e += 4) {
    const int srcn = csr[e];
    const uint4 v = *(const uint4*)(xb + (size_t)srcn * DD + li * 8);
    acc[0] += __uint_as_float(v.x << 16);
    acc[1] += __uint_as_float(v.x & 0xffff0000u);
    acc[2] += __uint_as_float(v.y << 16);
    acc[3] += __uint_as_float(v.y & 0xffff0000u);
    acc[4] += __uint_as_float(v.z << 16);
    acc[5] += __uint_as_float(v.z & 0xffff0000u);
    acc[6] += __uint_as_float(v.w << 16);
    acc[7] += __uint_as_float(v.w & 0xffff0000u);
  }
  // reduce the 4 edge-slots (lanes differing in bits 4,5)
#pragma unroll
  for (int j = 0; j < 8; ++j) acc[j] += __shfl_xor(acc[j], 16, 64);
#pragma unroll
  for (int j = 0; j < 8; ++j) acc[j] += __shfl_xor(acc[j], 32, 64);
  if (eo == 0) {
    const float sc = invdeg[node];
    u16 r[8];
#pragma unroll
    for (int j = 0; j < 8; ++j) r[j] = f2b(acc[j] * sc);
    uint4 o;
    o.x = (u32)r[0] | ((u32)r[1] << 16);
    o.y = (u32)r[2] | ((u32)r[3] << 16);
    o.z = (u32)r[4] | ((u32)r[5] << 16);
    o.w = (u32)r[6] | ((u32)r[7] << 16);
    *(uint4*)(outb + (size_t)node * DD + li * 8) = o;
  }
}

// ---------------- MFMA GEMM: out = [A1|A2] @ Wt^T + b (+relu) ----------------
// A1,A2: [NN][128] bf16. Wt: [128][256] bf16 (row n = output col, k = 0..255).
// Block: 256 thr = 4 waves, 64 rows x 128 cols. Wave w: rows m0+w*16..+15.
template <int OUT_BF16, int RELU>
__global__ __launch_bounds__(256) void mm_kernel(
    const u16* __restrict__ A1, const u16* __restrict__ A2,
    const u16* __restrict__ Wt, const float* __restrict__ bias,
    void* __restrict__ outp) {
  const int t = threadIdx.x;
  const int w = t >> 6;
  const int lane = t & 63;
  const int r = lane & 15;   // A row-in-tile / B col-in-tile
  const int g = lane >> 4;   // k-group (8 contiguous k each)
  const int m0 = blockIdx.x * 64 + w * 16;

  f32x4 acc[8];
#pragma unroll
  for (int i = 0; i < 8; ++i) acc[i] = (f32x4){0.f, 0.f, 0.f, 0.f};

#pragma unroll
  for (int ks = 0; ks < 8; ++ks) {
    const int kk = ks * 32;
    const u16* Abase = (ks < 4) ? A1 : A2;
    const int ka = kk & 127;
    const short8v afr =
        *(const short8v*)(Abase + (size_t)(m0 + r) * DD + ka + g * 8);
#pragma unroll
    for (int nt = 0; nt < 8; ++nt) {
      const short8v bfr =
          *(const short8v*)(Wt + (size_t)(nt * 16 + r) * 256 + kk + g * 8);
      acc[nt] = __builtin_amdgcn_mfma_f32_16x16x32_bf16(afr, bfr, acc[nt], 0, 0, 0);
    }
  }

  // C/D layout: col = lane&15, row = (lane>>4)*4 + reg
  const int crow0 = m0 + g * 4;
#pragma unroll
  for (int nt = 0; nt < 8; ++nt) {
    const int col = nt * 16 + r;
    const float bv = bias[col];
#pragma unroll
    for (int reg = 0; reg < 4; ++reg) {
      const int row = crow0 + reg;
      float o = acc[nt][reg] + bv;
      if (RELU) o = fmaxf(o, 0.f);
      if (OUT_BF16)
        ((u16*)outp)[(size_t)row * DD + col] = f2b(o);
      else
        ((float*)outp)[(size_t)row * DD + col] = o;
    }
  }
}

// ---------------- launch ----------------
extern "C" void kernel_launch(void* const* d_in, const int* in_sizes, int n_in,
                              void* d_out, int out_size, void* d_ws, size_t ws_size,
                              hipStream_t stream) {
  const float* x = (const float*)d_in[0];
  const int* ei = (const int*)d_in[1];
  const int* srcv = ei;          // edge_index[0]
  const int* dstv = ei + NE;     // edge_index[1]
  const float* W1l = (const float*)d_in[2];
  const float* b1 = (const float*)d_in[3];
  const float* W1r = (const float*)d_in[4];
  const float* W2l = (const float*)d_in[5];
  const float* b2 = (const float*)d_in[6];
  const float* W2r = (const float*)d_in[7];
  float* out = (float*)d_out;

  char* ws = (char*)d_ws;
  int* deg = (int*)(ws + 0);               // 160000 B (dead after scan3 -> wt2)
  int* rowptr = (int*)(ws + 160256);       // 160004 B
  int* cursor = (int*)(ws + 320512);       // 160000 B (dead after fill -> wt1)
  int* bsum = (int*)(ws + 480512);         // 4096 B
  float* invdeg = (float*)(ws + 484608);   // 160000 B
  int* csr = (int*)(ws + 644608);          // 2560000 B
  u16* xb = (u16*)(ws + 3205376);          // 10240000 B
  u16* aggb = (u16*)(ws + 13445376);       // 10240000 B
  u16* hb = (u16*)(ws + 23685376);         // 10240000 B  (end ~33.9 MB)
  u16* wt1 = (u16*)(ws + 320512);          // 65536 B over cursor
  u16* wt2 = (u16*)(ws + 0);               // 65536 B over deg

  const int nbN = (NN + 255) / 256;   // 157
  const int nbE = NE / 256;           // 2500

  hipMemsetAsync(deg, 0, NN * sizeof(int), stream);
  hist_kernel<<<nbE, 256, 0, stream>>>(dstv, deg);
  scan1_kernel<<<nbN, 256, 0, stream>>>(deg, rowptr, bsum);
  scan2_kernel<<<1, 256, 0, stream>>>(bsum, nbN);
  scan3_kernel<<<nbN, 256, 0, stream>>>(rowptr, bsum, deg, invdeg, cursor);
  fill_kernel<<<nbE, 256, 0, stream>>>(srcv, dstv, cursor, csr);
  tob_kernel<<<NN * DD / 4 / 256, 256, 0, stream>>>(x, xb);
  // weight prep (deg/cursor regions are dead now)
  wcvt_kernel<<<128, 256, 0, stream>>>(W1l, W1r, wt1);
  wcvt_kernel<<<128, 256, 0, stream>>>(W2l, W2r, wt2);

  // layer 1
  agg_kernel<<<NN / 4, 256, 0, stream>>>(xb, rowptr, csr, invdeg, aggb);
  mm_kernel<1, 1><<<NN / 64, 256, 0, stream>>>(aggb, xb, wt1, b1, (void*)hb);
  // layer 2
  agg_kernel<<<NN / 4, 256, 0, stream>>>(hb, rowptr, csr, invdeg, aggb);
  mm_kernel<0, 0><<<NN / 64, 256, 0, stream>>>(aggb, hb, wt2, b2, (void*)out);
}

// Round 3
// 191.099 us; speedup vs baseline: 1.2751x; 1.0218x over previous
//
#include <hip/hip_runtime.h>
#include <hip/hip_bf16.h>

#define NN 40000
#define NE 640000
#define DD 128

typedef unsigned short u16;
typedef unsigned int u32;
typedef __attribute__((ext_vector_type(8))) short short8v;
typedef __attribute__((ext_vector_type(4))) float f32x4;

__device__ __forceinline__ float b2f(u32 bits16) {
  return __uint_as_float(bits16 << 16);
}
__device__ __forceinline__ u16 f2b(float f) {
  __hip_bfloat16 h = __float2bfloat16(f);
  return *reinterpret_cast<u16*>(&h);
}

// ---------------- CSR build ----------------
__global__ void zero_kernel(int* __restrict__ p, int n) {
  int i = blockIdx.x * 256 + threadIdx.x;
  if (i < n) p[i] = 0;
}

__global__ void hist_kernel(const int* __restrict__ dst, int* __restrict__ deg) {
  int e = blockIdx.x * 256 + threadIdx.x;
  if (e < NE) atomicAdd(&deg[dst[e]], 1);
}

__global__ void scan1_kernel(const int* __restrict__ deg, int* __restrict__ rowptr,
                             int* __restrict__ bsum) {
  __shared__ int s[256];
  int tid = threadIdx.x;
  int i = blockIdx.x * 256 + tid;
  int v = (i < NN) ? deg[i] : 0;
  s[tid] = v;
  __syncthreads();
  for (int off = 1; off < 256; off <<= 1) {
    int t = (tid >= off) ? s[tid - off] : 0;
    __syncthreads();
    s[tid] += t;
    __syncthreads();
  }
  if (i < NN) rowptr[i + 1] = s[tid];
  if (tid == 255) bsum[blockIdx.x] = s[255];
}

__global__ void scan2_kernel(int* __restrict__ bsum, int nb) {
  __shared__ int s[256];
  int tid = threadIdx.x;
  int v = (tid < nb) ? bsum[tid] : 0;
  s[tid] = v;
  __syncthreads();
  for (int off = 1; off < 256; off <<= 1) {
    int t = (tid >= off) ? s[tid - off] : 0;
    __syncthreads();
    s[tid] += t;
    __syncthreads();
  }
  if (tid < nb) bsum[tid] = s[tid] - v;  // exclusive
}

__global__ void scan3_kernel(int* __restrict__ rowptr, const int* __restrict__ bsum,
                             const int* __restrict__ deg, float* __restrict__ invdeg,
                             int* __restrict__ cursor) {
  int i = blockIdx.x * 256 + threadIdx.x;
  if (i < NN) {
    int v = rowptr[i + 1] + bsum[i >> 8];
    rowptr[i + 1] = v;
    if (i + 1 < NN) cursor[i + 1] = v;
    int d = deg[i];
    invdeg[i] = 1.0f / (float)(d > 1 ? d : 1);
  }
  if (i == 0) {
    rowptr[0] = 0;
    cursor[0] = 0;
  }
}

__global__ void fill_kernel(const int* __restrict__ src, const int* __restrict__ dst,
                            int* __restrict__ cursor, int* __restrict__ csr) {
  int e = blockIdx.x * 256 + threadIdx.x;
  if (e < NE) {
    int d = dst[e];
    int p = atomicAdd(&cursor[d], 1);
    csr[p] = src[e];
  }
}

// ---------------- dtype prep ----------------
__global__ void tob_kernel(const float* __restrict__ x, u16* __restrict__ xb) {
  int i = blockIdx.x * 256 + threadIdx.x;  // 4 elems/thread, exact fit
  float4 v = *(const float4*)(x + (size_t)i * 4);
  ushort4 o;
  o.x = f2b(v.x); o.y = f2b(v.y); o.z = f2b(v.z); o.w = f2b(v.w);
  *(ushort4*)(xb + (size_t)i * 4) = o;
}

// Wt[n][k] bf16 for both layers in one launch. i in [0, 2*32768).
__global__ void wcvt_kernel(const float* __restrict__ W1l, const float* __restrict__ W1r,
                            const float* __restrict__ W2l, const float* __restrict__ W2r,
                            u16* __restrict__ Wt1, u16* __restrict__ Wt2) {
  int i = blockIdx.x * 256 + threadIdx.x;  // 256 blocks
  int layer = i >> 15;
  int j = i & 32767;
  int n = j >> 8, k = j & 255;
  const float* W = layer ? ((k < 128) ? W2l : W2r) : ((k < 128) ? W1l : W1r);
  u16* Wt = layer ? Wt2 : Wt1;
  int kk = k & 127;
  Wt[j] = f2b(W[(size_t)kk * 128 + n]);
}

// ---------------- aggregation: 1 wave per node, 4 edge-slots x 16 lanes ----------------
__global__ __launch_bounds__(256) void agg_kernel(
    const u16* __restrict__ xb, const int* __restrict__ rowptr,
    const int* __restrict__ csr, const float* __restrict__ invdeg,
    u16* __restrict__ outb) {
  const int t = threadIdx.x;
  const int lane = t & 63;
  const int li = lane & 15;   // feature group: 8 bf16 at li*8
  const int eo = lane >> 4;   // edge slot 0..3
  const int node = blockIdx.x * 4 + (t >> 6);
  const int s0 = rowptr[node];
  const int s1 = rowptr[node + 1];
  float acc[8] = {0.f, 0.f, 0.f, 0.f, 0.f, 0.f, 0.f, 0.f};
  int e = s0 + eo;
  int srcn = (e < s1) ? csr[e] : 0;
  while (e < s1) {
    const int enext = e + 4;
    const int srcn_next = (enext < s1) ? csr[enext] : 0;  // prefetch next index
    const uint4 v = *(const uint4*)(xb + (size_t)srcn * DD + li * 8);
    acc[0] += __uint_as_float(v.x << 16);
    acc[1] += __uint_as_float(v.x & 0xffff0000u);
    acc[2] += __uint_as_float(v.y << 16);
    acc[3] += __uint_as_float(v.y & 0xffff0000u);
    acc[4] += __uint_as_float(v.z << 16);
    acc[5] += __uint_as_float(v.z & 0xffff0000u);
    acc[6] += __uint_as_float(v.w << 16);
    acc[7] += __uint_as_float(v.w & 0xffff0000u);
    srcn = srcn_next;
    e = enext;
  }
  // reduce the 4 edge-slots (lanes differing in bits 4,5)
#pragma unroll
  for (int j = 0; j < 8; ++j) acc[j] += __shfl_xor(acc[j], 16, 64);
#pragma unroll
  for (int j = 0; j < 8; ++j) acc[j] += __shfl_xor(acc[j], 32, 64);
  if (eo == 0) {
    const float sc = invdeg[node];
    u16 r[8];
#pragma unroll
    for (int j = 0; j < 8; ++j) r[j] = f2b(acc[j] * sc);
    uint4 o;
    o.x = (u32)r[0] | ((u32)r[1] << 16);
    o.y = (u32)r[2] | ((u32)r[3] << 16);
    o.z = (u32)r[4] | ((u32)r[5] << 16);
    o.w = (u32)r[6] | ((u32)r[7] << 16);
    *(uint4*)(outb + (size_t)node * DD + li * 8) = o;
  }
}

// ---------------- MFMA GEMM: out = [A1|A2] @ Wt^T + b (+relu) ----------------
template <int OUT_BF16, int RELU>
__global__ __launch_bounds__(256) void mm_kernel(
    const u16* __restrict__ A1, const u16* __restrict__ A2,
    const u16* __restrict__ Wt, const float* __restrict__ bias,
    void* __restrict__ outp) {
  const int t = threadIdx.x;
  const int w = t >> 6;
  const int lane = t & 63;
  const int r = lane & 15;   // A row-in-tile / B col-in-tile
  const int g = lane >> 4;   // k-group (8 contiguous k each)
  const int m0 = blockIdx.x * 64 + w * 16;

  f32x4 acc[8];
#pragma unroll
  for (int i = 0; i < 8; ++i) acc[i] = (f32x4){0.f, 0.f, 0.f, 0.f};

#pragma unroll
  for (int ks = 0; ks < 8; ++ks) {
    const int kk = ks * 32;
    const u16* Abase = (ks < 4) ? A1 : A2;
    const int ka = kk & 127;
    const short8v afr =
        *(const short8v*)(Abase + (size_t)(m0 + r) * DD + ka + g * 8);
#pragma unroll
    for (int nt = 0; nt < 8; ++nt) {
      const short8v bfr =
          *(const short8v*)(Wt + (size_t)(nt * 16 + r) * 256 + kk + g * 8);
      acc[nt] = __builtin_amdgcn_mfma_f32_16x16x32_bf16(afr, bfr, acc[nt], 0, 0, 0);
    }
  }

  // C/D layout: col = lane&15, row = (lane>>4)*4 + reg
  const int crow0 = m0 + g * 4;
#pragma unroll
  for (int nt = 0; nt < 8; ++nt) {
    const int col = nt * 16 + r;
    const float bv = bias[col];
#pragma unroll
    for (int reg = 0; reg < 4; ++reg) {
      const int row = crow0 + reg;
      float o = acc[nt][reg] + bv;
      if (RELU) o = fmaxf(o, 0.f);
      if (OUT_BF16)
        ((u16*)outp)[(size_t)row * DD + col] = f2b(o);
      else
        ((float*)outp)[(size_t)row * DD + col] = o;
    }
  }
}

// ---------------- launch ----------------
extern "C" void kernel_launch(void* const* d_in, const int* in_sizes, int n_in,
                              void* d_out, int out_size, void* d_ws, size_t ws_size,
                              hipStream_t stream) {
  const float* x = (const float*)d_in[0];
  const int* ei = (const int*)d_in[1];
  const int* srcv = ei;          // edge_index[0]
  const int* dstv = ei + NE;     // edge_index[1]
  const float* W1l = (const float*)d_in[2];
  const float* b1 = (const float*)d_in[3];
  const float* W1r = (const float*)d_in[4];
  const float* W2l = (const float*)d_in[5];
  const float* b2 = (const float*)d_in[6];
  const float* W2r = (const float*)d_in[7];
  float* out = (float*)d_out;

  char* ws = (char*)d_ws;
  int* deg = (int*)(ws + 0);               // 160000 B (dead after scan3 -> wt2)
  int* rowptr = (int*)(ws + 160256);       // 160004 B
  int* cursor = (int*)(ws + 320512);       // 160000 B (dead after fill -> wt1)
  int* bsum = (int*)(ws + 480512);         // 4096 B
  float* invdeg = (float*)(ws + 484608);   // 160000 B
  int* csr = (int*)(ws + 644608);          // 2560000 B
  u16* xb = (u16*)(ws + 3205376);          // 10240000 B
  u16* aggb = (u16*)(ws + 13445376);       // 10240000 B
  u16* hb = (u16*)(ws + 23685376);         // 10240000 B  (end ~33.9 MB)
  u16* wt1 = (u16*)(ws + 320512);          // 65536 B over cursor
  u16* wt2 = (u16*)(ws + 0);               // 65536 B over deg

  const int nbN = (NN + 255) / 256;   // 157
  const int nbE = NE / 256;           // 2500

  zero_kernel<<<nbN, 256, 0, stream>>>(deg, NN);
  hist_kernel<<<nbE, 256, 0, stream>>>(dstv, deg);
  scan1_kernel<<<nbN, 256, 0, stream>>>(deg, rowptr, bsum);
  scan2_kernel<<<1, 256, 0, stream>>>(bsum, nbN);
  scan3_kernel<<<nbN, 256, 0, stream>>>(rowptr, bsum, deg, invdeg, cursor);
  fill_kernel<<<nbE, 256, 0, stream>>>(srcv, dstv, cursor, csr);
  tob_kernel<<<NN * DD / 4 / 256, 256, 0, stream>>>(x, xb);
  wcvt_kernel<<<256, 256, 0, stream>>>(W1l, W1r, W2l, W2r, wt1, wt2);

  // layer 1
  agg_kernel<<<NN / 4, 256, 0, stream>>>(xb, rowptr, csr, invdeg, aggb);
  mm_kernel<1, 1><<<NN / 64, 256, 0, stream>>>(aggb, xb, wt1, b1, (void*)hb);
  // layer 2
  agg_kernel<<<NN / 4, 256, 0, stream>>>(hb, rowptr, csr, invdeg, aggb);
  mm_kernel<0, 0><<<NN / 64, 256, 0, stream>>>(aggb, hb, wt2, b2, (void*)out);
}